// Round 5
// baseline (253.552 us; speedup 1.0000x reference)
//
#include <hip/hip_runtime.h>
#include <hip/hip_bf16.h>

typedef __bf16 bf16_t;
typedef __bf16 bf16x8 __attribute__((ext_vector_type(8)));
typedef __bf16 bf16x4 __attribute__((ext_vector_type(4)));
typedef float f32x4 __attribute__((ext_vector_type(4)));

#define IN_DIM 21
#define HID 512
#define OUT_DIM 21
#define M_TILE 64
#define THREADS 512   // 8 waves, f=4 (64 hid/wave); target 2 blocks/CU (<=128 regs/wave)

// ---- prep: fp32 -> bf16 fragment-major weights, vectorized (bf16x8 stores) ----
// frag element (idx = tile*16 + (lane&15), k = k0 + (lane>>4)*8 + j) at base + lane*8 + j.
// W2f: [kstep(16)][htile(32)][512]   W1f: [htile(32)][512] (k>=21 zero)
// W3f: [kstep(16)][otile(2)][512]    (o>=21 zero)
__global__ void prep_kernel(const float* __restrict__ W1, const float* __restrict__ W2,
                            const float* __restrict__ W3,
                            bf16_t* __restrict__ W1f, bf16_t* __restrict__ W2f,
                            bf16_t* __restrict__ W3f) {
    int t8 = blockIdx.x * blockDim.x + threadIdx.x;   // one bf16x8 chunk per thread
    if (t8 < 32768) {                                 // W2f: 262144 elems / 8
        int lane = t8 & 63, ht = (t8 >> 6) & 31, ks = t8 >> 11;
        int n = ht * 16 + (lane & 15), k = ks * 32 + (lane >> 4) * 8;
        const float* src = W2 + n * HID + k;
        bf16x8 v;
        #pragma unroll
        for (int j = 0; j < 8; ++j) v[j] = (bf16_t)src[j];
        *reinterpret_cast<bf16x8*>(W2f + t8 * 8) = v;
    } else if (t8 < 32768 + 2048) {                   // W1f: 16384 / 8
        int t = t8 - 32768;
        int lane = t & 63, ht = t >> 6;
        int n = ht * 16 + (lane & 15), k0 = (lane >> 4) * 8;
        bf16x8 v;
        #pragma unroll
        for (int j = 0; j < 8; ++j) {
            int k = k0 + j;
            v[j] = (k < IN_DIM) ? (bf16_t)W1[n * IN_DIM + k] : (bf16_t)0.0f;
        }
        *reinterpret_cast<bf16x8*>(W1f + t * 8) = v;
    } else if (t8 < 32768 + 4096) {                   // W3f: 16384 / 8
        int t = t8 - 32768 - 2048;
        int lane = t & 63, ot = (t >> 6) & 1, ks = t >> 7;
        int o = ot * 16 + (lane & 15), k = ks * 32 + (lane >> 4) * 8;
        bf16x8 v;
        #pragma unroll
        for (int j = 0; j < 8; ++j)
            v[j] = (o < OUT_DIM) ? (bf16_t)W3[o * HID + k + j] : (bf16_t)0.0f;
        *reinterpret_cast<bf16x8*>(W3f + t * 8) = v;
    }
}

// ---- fused MLP + loss; activations in fragment-major LDS (conflict-free) ----
__global__ __launch_bounds__(THREADS, 4)
void fused_kernel(const float* __restrict__ V, const float* __restrict__ gt,
                  const float* __restrict__ b1, const float* __restrict__ b2,
                  const float* __restrict__ b3,
                  const bf16_t* __restrict__ W1f, const bf16_t* __restrict__ W2f,
                  const bf16_t* __restrict__ W3f, float* __restrict__ accum,
                  unsigned int* __restrict__ counter, float* __restrict__ out,
                  int nblocks) {
    // hfrag[kgroup][btile][lane][j]: element (batch = btile*16 + (lane&15),
    //   hid = kgroup*32 + (lane>>4)*8 + j). Wave B-frag read = contiguous 1 KB.
    __shared__ __align__(16) bf16_t hfrag[16][4][64][8];   // 64 KB, h1 then h2
    __shared__ __align__(16) bf16_t vfrag[4][64][8];       // 4 KB, V tile
    __shared__ float redbuf[16];

    const int tid  = threadIdx.x;
    const int wave = tid >> 6;       // 0..7; owns hid [wave*64, wave*64+64)
    const int lane = tid & 63;
    const int quad = lane >> 4;
    const int l16  = lane & 15;
    const long row0 = (long)blockIdx.x * M_TILE;

    // phase 0: stage V tile into vfrag (fragment-major, k cols >=21 zero)
    if (tid < 256) {
        int nt = tid >> 6, ln = tid & 63;
        int batch = nt * 16 + (ln & 15);
        int k0 = (ln >> 4) * 8;
        const float* src = V + (row0 + batch) * IN_DIM;
        bf16x8 v;
        #pragma unroll
        for (int j = 0; j < 8; ++j) {
            int k = k0 + j;
            v[j] = (k < IN_DIM) ? (bf16_t)src[k] : (bf16_t)0.0f;
        }
        *reinterpret_cast<bf16x8*>(&vfrag[nt][ln][0]) = v;
    }
    __syncthreads();

    // phase 1: h1 = relu(W1 @ V^T + b1); D[m=hid][n=batch]
    {
        bf16x8 bfr[4];
        #pragma unroll
        for (int nt = 0; nt < 4; ++nt)
            bfr[nt] = *reinterpret_cast<const bf16x8*>(&vfrag[nt][lane][0]);
        #pragma unroll
        for (int mt = 0; mt < 4; ++mt) {
            bf16x8 a = *reinterpret_cast<const bf16x8*>(W1f + (wave * 4 + mt) * 512 + lane * 8);
            f32x4 bias = *reinterpret_cast<const f32x4*>(b1 + wave * 64 + mt * 16 + quad * 4);
            #pragma unroll
            for (int nt = 0; nt < 4; ++nt) {
                f32x4 c = {0.0f, 0.0f, 0.0f, 0.0f};
                c = __builtin_amdgcn_mfma_f32_16x16x32_bf16(a, bfr[nt], c, 0, 0, 0);
                bf16x4 hv;
                #pragma unroll
                for (int r = 0; r < 4; ++r) {
                    float v = c[r] + bias[r];
                    hv[r] = (bf16_t)(v > 0.0f ? v : 0.0f);
                }
                // hid = wave*64 + mt*16 + quad*4 + r  -> fragment-major slot
                *reinterpret_cast<bf16x4*>(
                    &hfrag[2 * wave + (mt >> 1)][nt]
                          [l16 + 16 * ((mt & 1) * 2 + (quad >> 1))][(quad & 1) * 4]) = hv;
            }
        }
    }
    __syncthreads();

    // phase 2: h2 = relu(W2 @ h1^T + b2). Per wave: 64 hid x 64 batch, K=512.
    f32x4 acc[4][4];
    #pragma unroll
    for (int mt = 0; mt < 4; ++mt)
        #pragma unroll
        for (int nt = 0; nt < 4; ++nt)
            acc[mt][nt] = (f32x4){0.0f, 0.0f, 0.0f, 0.0f};

    {
        const bf16_t* wp = W2f + (wave * 4) * 512 + lane * 8;  // +mt*512, +ks*16384
        bf16x8 a0 = *reinterpret_cast<const bf16x8*>(wp);
        bf16x8 a1 = *reinterpret_cast<const bf16x8*>(wp + 512);
        bf16x8 a2 = *reinterpret_cast<const bf16x8*>(wp + 1024);
        bf16x8 a3 = *reinterpret_cast<const bf16x8*>(wp + 1536);
        #pragma unroll
        for (int ks = 0; ks < 16; ++ks) {
            bf16x8 c0 = a0, c1 = a1, c2 = a2, c3 = a3;
            if (ks < 15) {   // depth-1 prefetch of next K-step's A-frags (L2)
                const bf16_t* np = wp + (ks + 1) * 16384;
                a0 = *reinterpret_cast<const bf16x8*>(np);
                a1 = *reinterpret_cast<const bf16x8*>(np + 512);
                a2 = *reinterpret_cast<const bf16x8*>(np + 1024);
                a3 = *reinterpret_cast<const bf16x8*>(np + 1536);
            }
            bf16x8 bfr[4];
            #pragma unroll
            for (int nt = 0; nt < 4; ++nt)
                bfr[nt] = *reinterpret_cast<const bf16x8*>(&hfrag[ks][nt][lane][0]);
            #pragma unroll
            for (int nt = 0; nt < 4; ++nt) {
                acc[0][nt] = __builtin_amdgcn_mfma_f32_16x16x32_bf16(c0, bfr[nt], acc[0][nt], 0, 0, 0);
                acc[1][nt] = __builtin_amdgcn_mfma_f32_16x16x32_bf16(c1, bfr[nt], acc[1][nt], 0, 0, 0);
                acc[2][nt] = __builtin_amdgcn_mfma_f32_16x16x32_bf16(c2, bfr[nt], acc[2][nt], 0, 0, 0);
                acc[3][nt] = __builtin_amdgcn_mfma_f32_16x16x32_bf16(c3, bfr[nt], acc[3][nt], 0, 0, 0);
            }
        }
    }
    __syncthreads();   // all h1 reads complete before overwrite

    #pragma unroll
    for (int t = 0; t < 4; ++t) {
        f32x4 bias = *reinterpret_cast<const f32x4*>(b2 + wave * 64 + t * 16 + quad * 4);
        #pragma unroll
        for (int nt = 0; nt < 4; ++nt) {
            bf16x4 hv;
            #pragma unroll
            for (int r = 0; r < 4; ++r) {
                float v = acc[t][nt][r] + bias[r];
                hv[r] = (bf16_t)(v > 0.0f ? v : 0.0f);
            }
            *reinterpret_cast<bf16x4*>(
                &hfrag[2 * wave + (t >> 1)][nt]
                      [l16 + 16 * ((t & 1) * 2 + (quad >> 1))][(quad & 1) * 4]) = hv;
        }
    }
    __syncthreads();

    // phase 3: out = W3 @ h2^T + b3. 8 jobs = 2 o-tiles x 4 batch-tiles, one/wave.
    {
        const int ot = wave & 1, ntj = wave >> 1;
        const bf16_t* wp3 = W3f + ot * 512 + lane * 8;   // +ks*1024
        f32x4 acc3 = {0.0f, 0.0f, 0.0f, 0.0f};
        bf16x8 a = *reinterpret_cast<const bf16x8*>(wp3);
        #pragma unroll
        for (int ks = 0; ks < 16; ++ks) {
            bf16x8 ac = a;
            if (ks < 15) a = *reinterpret_cast<const bf16x8*>(wp3 + (ks + 1) * 1024);
            bf16x8 b = *reinterpret_cast<const bf16x8*>(&hfrag[ks][ntj][lane][0]);
            acc3 = __builtin_amdgcn_mfma_f32_16x16x32_bf16(ac, b, acc3, 0, 0, 0);
        }

        float num = 0.0f, den = 0.0f;
        long brow = row0 + ntj * 16 + l16;
        #pragma unroll
        for (int r = 0; r < 4; ++r) {
            int c = ot * 16 + quad * 4 + r;
            if (c < OUT_DIM) {
                float pred = acc3[r] + b3[c];
                float g = gt[brow * OUT_DIM + c];
                if (g > -5000.0f) {
                    float w = (floorf(pred * 2.0f) == floorf(g * 2.0f)) ? 0.5f : 1.0f;
                    num += fabsf(pred * w - g * w);
                    den += 1.0f;
                }
            }
        }
        #pragma unroll
        for (int off = 32; off > 0; off >>= 1) {
            num += __shfl_down(num, off);
            den += __shfl_down(den, off);
        }
        if (lane == 0) { redbuf[wave * 2] = num; redbuf[wave * 2 + 1] = den; }
    }
    __syncthreads();
    if (tid == 0) {
        float n8 = 0.0f, d8 = 0.0f;
        #pragma unroll
        for (int w = 0; w < 8; ++w) { n8 += redbuf[w * 2]; d8 += redbuf[w * 2 + 1]; }
        atomicAdd(accum, n8);
        atomicAdd(accum + 1, d8);
        __threadfence();
        unsigned int ticket = atomicAdd(counter, 1u);
        if (ticket == (unsigned int)(nblocks - 1)) {
            float tn = atomicAdd(accum, 0.0f);      // device-scope atomic read
            float td = atomicAdd(accum + 1, 0.0f);
            out[0] = tn / td;
        }
    }
}

extern "C" void kernel_launch(void* const* d_in, const int* in_sizes, int n_in,
                              void* d_out, int out_size, void* d_ws, size_t ws_size,
                              hipStream_t stream) {
    const float* V  = (const float*)d_in[0];
    const float* gt = (const float*)d_in[1];
    const float* W1 = (const float*)d_in[2];
    const float* b1 = (const float*)d_in[3];
    const float* W2 = (const float*)d_in[4];
    const float* b2 = (const float*)d_in[5];
    const float* W3 = (const float*)d_in[6];
    const float* b3 = (const float*)d_in[7];
    float* out = (float*)d_out;

    char* ws = (char*)d_ws;
    float* accum = (float*)ws;                     // [0]=num, [1]=den
    unsigned int* counter = (unsigned int*)(ws + 8);
    bf16_t* W2f = (bf16_t*)(ws + 16);
    bf16_t* W1f = (bf16_t*)(ws + 16 + 512 * 512 * 2);
    bf16_t* W3f = (bf16_t*)(ws + 16 + 512 * 512 * 2 + 32 * 512 * 2);

    int Brows = in_sizes[0] / IN_DIM;   // 131072
    int grid = Brows / M_TILE;          // 2048

    hipMemsetAsync(ws, 0, 16, stream);  // num, den, counter
    prep_kernel<<<72, 512, 0, stream>>>(W1, W2, W3, W1f, W2f, W3f);
    fused_kernel<<<grid, THREADS, 0, stream>>>(V, gt, b1, b2, b3, W1f, W2f, W3f,
                                               accum, counter, out, grid);
}

// Round 6
// 245.532 us; speedup vs baseline: 1.0327x; 1.0327x over previous
//
#include <hip/hip_runtime.h>
#include <hip/hip_bf16.h>

typedef __bf16 bf16_t;
typedef __bf16 bf16x8 __attribute__((ext_vector_type(8)));
typedef __bf16 bf16x4 __attribute__((ext_vector_type(4)));
typedef float f32x4 __attribute__((ext_vector_type(4)));

#define IN_DIM 21
#define HID 512
#define OUT_DIM 21
#define M_TILE 64
#define THREADS 512   // 8 waves, f=4 (64 hid/wave); 2 blocks/CU (128 regs/wave, spill-free)

// ---- prep: fp32 -> bf16 fragment-major weights, vectorized (bf16x8 stores) ----
// frag element (idx = tile*16 + (lane&15), k = k0 + (lane>>4)*8 + j) at base + lane*8 + j.
// W2f: [kstep(16)][htile(32)][512]   W1f: [htile(32)][512] (k>=21 zero)
// W3f: [kstep(16)][otile(2)][512]    (o>=21 zero)
__global__ void prep_kernel(const float* __restrict__ W1, const float* __restrict__ W2,
                            const float* __restrict__ W3,
                            bf16_t* __restrict__ W1f, bf16_t* __restrict__ W2f,
                            bf16_t* __restrict__ W3f) {
    int t8 = blockIdx.x * blockDim.x + threadIdx.x;   // one bf16x8 chunk per thread
    if (t8 < 32768) {                                 // W2f: 262144 elems / 8
        int lane = t8 & 63, ht = (t8 >> 6) & 31, ks = t8 >> 11;
        int n = ht * 16 + (lane & 15), k = ks * 32 + (lane >> 4) * 8;
        const float* src = W2 + n * HID + k;
        bf16x8 v;
        #pragma unroll
        for (int j = 0; j < 8; ++j) v[j] = (bf16_t)src[j];
        *reinterpret_cast<bf16x8*>(W2f + t8 * 8) = v;
    } else if (t8 < 32768 + 2048) {                   // W1f: 16384 / 8
        int t = t8 - 32768;
        int lane = t & 63, ht = t >> 6;
        int n = ht * 16 + (lane & 15), k0 = (lane >> 4) * 8;
        bf16x8 v;
        #pragma unroll
        for (int j = 0; j < 8; ++j) {
            int k = k0 + j;
            v[j] = (k < IN_DIM) ? (bf16_t)W1[n * IN_DIM + k] : (bf16_t)0.0f;
        }
        *reinterpret_cast<bf16x8*>(W1f + t * 8) = v;
    } else if (t8 < 32768 + 4096) {                   // W3f: 16384 / 8
        int t = t8 - 32768 - 2048;
        int lane = t & 63, ot = (t >> 6) & 1, ks = t >> 7;
        int o = ot * 16 + (lane & 15), k = ks * 32 + (lane >> 4) * 8;
        bf16x8 v;
        #pragma unroll
        for (int j = 0; j < 8; ++j)
            v[j] = (o < OUT_DIM) ? (bf16_t)W3[o * HID + k + j] : (bf16_t)0.0f;
        *reinterpret_cast<bf16x8*>(W3f + t * 8) = v;
    }
}

// ---- fused MLP + loss; fragment-major LDS; spill-proofed K-loop ----
__global__ __launch_bounds__(THREADS, 4)
void fused_kernel(const float* __restrict__ V, const float* __restrict__ gt,
                  const float* __restrict__ b1, const float* __restrict__ b2,
                  const float* __restrict__ b3,
                  const bf16_t* __restrict__ W1f, const bf16_t* __restrict__ W2f,
                  const bf16_t* __restrict__ W3f, float* __restrict__ accum,
                  unsigned int* __restrict__ counter, float* __restrict__ out,
                  int nblocks) {
    // hfrag[kgroup][btile][lane][j]: element (batch = btile*16 + (lane&15),
    //   hid = kgroup*32 + (lane>>4)*8 + j). Wave B-frag read = contiguous 1 KB.
    __shared__ __align__(16) bf16_t hfrag[16][4][64][8];   // 64 KB, h1 then h2
    __shared__ __align__(16) bf16_t vfrag[4][64][8];       // 4 KB, V tile
    __shared__ float redbuf[16];

    const int tid  = threadIdx.x;
    const int wave = tid >> 6;       // 0..7; owns hid [wave*64, wave*64+64)
    const int lane = tid & 63;
    const int quad = lane >> 4;
    const int l16  = lane & 15;
    const long row0 = (long)blockIdx.x * M_TILE;

    // phase 0: stage V tile into vfrag (fragment-major, k cols >=21 zero)
    if (tid < 256) {
        int nt = tid >> 6, ln = tid & 63;
        int batch = nt * 16 + (ln & 15);
        int k0 = (ln >> 4) * 8;
        const float* src = V + (row0 + batch) * IN_DIM;
        bf16x8 v;
        #pragma unroll
        for (int j = 0; j < 8; ++j) {
            int k = k0 + j;
            v[j] = (k < IN_DIM) ? (bf16_t)src[k] : (bf16_t)0.0f;
        }
        *reinterpret_cast<bf16x8*>(&vfrag[nt][ln][0]) = v;
    }
    __syncthreads();

    // phase 1: h1 = relu(W1 @ V^T + b1); D[m=hid][n=batch]
    {
        bf16x8 bfr[4];
        #pragma unroll
        for (int nt = 0; nt < 4; ++nt)
            bfr[nt] = *reinterpret_cast<const bf16x8*>(&vfrag[nt][lane][0]);
        #pragma unroll
        for (int mt = 0; mt < 4; ++mt) {
            bf16x8 a = *reinterpret_cast<const bf16x8*>(W1f + (wave * 4 + mt) * 512 + lane * 8);
            f32x4 bias = *reinterpret_cast<const f32x4*>(b1 + wave * 64 + mt * 16 + quad * 4);
            #pragma unroll
            for (int nt = 0; nt < 4; ++nt) {
                f32x4 c = {0.0f, 0.0f, 0.0f, 0.0f};
                c = __builtin_amdgcn_mfma_f32_16x16x32_bf16(a, bfr[nt], c, 0, 0, 0);
                bf16x4 hv;
                #pragma unroll
                for (int r = 0; r < 4; ++r) {
                    float v = c[r] + bias[r];
                    hv[r] = (bf16_t)(v > 0.0f ? v : 0.0f);
                }
                // hid = wave*64 + mt*16 + quad*4 + r  -> fragment-major slot
                *reinterpret_cast<bf16x4*>(
                    &hfrag[2 * wave + (mt >> 1)][nt]
                          [l16 + 16 * ((mt & 1) * 2 + (quad >> 1))][(quad & 1) * 4]) = hv;
            }
        }
    }
    __syncthreads();

    // phase 2: h2 = relu(W2 @ h1^T + b2). Per wave: 64 hid x 64 batch, K=512.
    f32x4 acc[4][4];
    #pragma unroll
    for (int mt = 0; mt < 4; ++mt)
        #pragma unroll
        for (int nt = 0; nt < 4; ++nt)
            acc[mt][nt] = (f32x4){0.0f, 0.0f, 0.0f, 0.0f};

    {
        const bf16_t* wp = W2f + (wave * 4) * 512 + lane * 8;   // advances 16384/ks
        const bf16_t* hp = &hfrag[0][0][lane][0];               // advances 2048/ks
        bf16x8 a0 = *reinterpret_cast<const bf16x8*>(wp);
        bf16x8 a1 = *reinterpret_cast<const bf16x8*>(wp + 512);
        bf16x8 a2 = *reinterpret_cast<const bf16x8*>(wp + 1024);
        bf16x8 a3 = *reinterpret_cast<const bf16x8*>(wp + 1536);
        #pragma unroll 1
        for (int ks = 0; ks < 15; ++ks) {
            bf16x8 c0 = a0, c1 = a1, c2 = a2, c3 = a3;
            wp += 16384;
            a0 = *reinterpret_cast<const bf16x8*>(wp);           // depth-1 prefetch
            a1 = *reinterpret_cast<const bf16x8*>(wp + 512);
            a2 = *reinterpret_cast<const bf16x8*>(wp + 1024);
            a3 = *reinterpret_cast<const bf16x8*>(wp + 1536);
            bf16x8 b0 = *reinterpret_cast<const bf16x8*>(hp);
            bf16x8 b1v = *reinterpret_cast<const bf16x8*>(hp + 512);
            bf16x8 b2v = *reinterpret_cast<const bf16x8*>(hp + 1024);
            bf16x8 b3v = *reinterpret_cast<const bf16x8*>(hp + 1536);
            hp += 2048;
            acc[0][0] = __builtin_amdgcn_mfma_f32_16x16x32_bf16(c0, b0,  acc[0][0], 0, 0, 0);
            acc[1][0] = __builtin_amdgcn_mfma_f32_16x16x32_bf16(c1, b0,  acc[1][0], 0, 0, 0);
            acc[2][0] = __builtin_amdgcn_mfma_f32_16x16x32_bf16(c2, b0,  acc[2][0], 0, 0, 0);
            acc[3][0] = __builtin_amdgcn_mfma_f32_16x16x32_bf16(c3, b0,  acc[3][0], 0, 0, 0);
            acc[0][1] = __builtin_amdgcn_mfma_f32_16x16x32_bf16(c0, b1v, acc[0][1], 0, 0, 0);
            acc[1][1] = __builtin_amdgcn_mfma_f32_16x16x32_bf16(c1, b1v, acc[1][1], 0, 0, 0);
            acc[2][1] = __builtin_amdgcn_mfma_f32_16x16x32_bf16(c2, b1v, acc[2][1], 0, 0, 0);
            acc[3][1] = __builtin_amdgcn_mfma_f32_16x16x32_bf16(c3, b1v, acc[3][1], 0, 0, 0);
            acc[0][2] = __builtin_amdgcn_mfma_f32_16x16x32_bf16(c0, b2v, acc[0][2], 0, 0, 0);
            acc[1][2] = __builtin_amdgcn_mfma_f32_16x16x32_bf16(c1, b2v, acc[1][2], 0, 0, 0);
            acc[2][2] = __builtin_amdgcn_mfma_f32_16x16x32_bf16(c2, b2v, acc[2][2], 0, 0, 0);
            acc[3][2] = __builtin_amdgcn_mfma_f32_16x16x32_bf16(c3, b2v, acc[3][2], 0, 0, 0);
            acc[0][3] = __builtin_amdgcn_mfma_f32_16x16x32_bf16(c0, b3v, acc[0][3], 0, 0, 0);
            acc[1][3] = __builtin_amdgcn_mfma_f32_16x16x32_bf16(c1, b3v, acc[1][3], 0, 0, 0);
            acc[2][3] = __builtin_amdgcn_mfma_f32_16x16x32_bf16(c2, b3v, acc[2][3], 0, 0, 0);
            acc[3][3] = __builtin_amdgcn_mfma_f32_16x16x32_bf16(c3, b3v, acc[3][3], 0, 0, 0);
        }
        { // peeled last k-step (ks = 15)
            bf16x8 b0 = *reinterpret_cast<const bf16x8*>(hp);
            bf16x8 b1v = *reinterpret_cast<const bf16x8*>(hp + 512);
            bf16x8 b2v = *reinterpret_cast<const bf16x8*>(hp + 1024);
            bf16x8 b3v = *reinterpret_cast<const bf16x8*>(hp + 1536);
            #pragma unroll
            for (int mt = 0; mt < 4; ++mt) {
                bf16x8 am = mt == 0 ? a0 : mt == 1 ? a1 : mt == 2 ? a2 : a3;
                acc[mt][0] = __builtin_amdgcn_mfma_f32_16x16x32_bf16(am, b0,  acc[mt][0], 0, 0, 0);
                acc[mt][1] = __builtin_amdgcn_mfma_f32_16x16x32_bf16(am, b1v, acc[mt][1], 0, 0, 0);
                acc[mt][2] = __builtin_amdgcn_mfma_f32_16x16x32_bf16(am, b2v, acc[mt][2], 0, 0, 0);
                acc[mt][3] = __builtin_amdgcn_mfma_f32_16x16x32_bf16(am, b3v, acc[mt][3], 0, 0, 0);
            }
        }
    }
    __syncthreads();   // all h1 reads complete before overwrite

    #pragma unroll
    for (int t = 0; t < 4; ++t) {
        f32x4 bias = *reinterpret_cast<const f32x4*>(b2 + wave * 64 + t * 16 + quad * 4);
        #pragma unroll
        for (int nt = 0; nt < 4; ++nt) {
            bf16x4 hv;
            #pragma unroll
            for (int r = 0; r < 4; ++r) {
                float v = acc[t][nt][r] + bias[r];
                hv[r] = (bf16_t)(v > 0.0f ? v : 0.0f);
            }
            *reinterpret_cast<bf16x4*>(
                &hfrag[2 * wave + (t >> 1)][nt]
                      [l16 + 16 * ((t & 1) * 2 + (quad >> 1))][(quad & 1) * 4]) = hv;
        }
    }
    __syncthreads();

    // phase 3: out = W3 @ h2^T + b3. 8 jobs = 2 o-tiles x 4 batch-tiles, one/wave.
    {
        const int ot = wave & 1, ntj = wave >> 1;
        const bf16_t* wp3 = W3f + ot * 512 + lane * 8;   // +ks*1024
        const bf16_t* hp3 = &hfrag[0][ntj][lane][0];     // +ks*2048
        f32x4 acc3 = {0.0f, 0.0f, 0.0f, 0.0f};
        #pragma unroll 1
        for (int ks = 0; ks < 16; ++ks) {
            bf16x8 a = *reinterpret_cast<const bf16x8*>(wp3);
            bf16x8 b = *reinterpret_cast<const bf16x8*>(hp3);
            wp3 += 1024;
            hp3 += 2048;
            acc3 = __builtin_amdgcn_mfma_f32_16x16x32_bf16(a, b, acc3, 0, 0, 0);
        }

        float num = 0.0f, den = 0.0f;
        long brow = row0 + ntj * 16 + l16;
        #pragma unroll
        for (int r = 0; r < 4; ++r) {
            int c = ot * 16 + quad * 4 + r;
            if (c < OUT_DIM) {
                float pred = acc3[r] + b3[c];
                float g = gt[brow * OUT_DIM + c];
                if (g > -5000.0f) {
                    float w = (floorf(pred * 2.0f) == floorf(g * 2.0f)) ? 0.5f : 1.0f;
                    num += fabsf(pred * w - g * w);
                    den += 1.0f;
                }
            }
        }
        #pragma unroll
        for (int off = 32; off > 0; off >>= 1) {
            num += __shfl_down(num, off);
            den += __shfl_down(den, off);
        }
        if (lane == 0) { redbuf[wave * 2] = num; redbuf[wave * 2 + 1] = den; }
    }
    __syncthreads();
    if (tid == 0) {
        float n8 = 0.0f, d8 = 0.0f;
        #pragma unroll
        for (int w = 0; w < 8; ++w) { n8 += redbuf[w * 2]; d8 += redbuf[w * 2 + 1]; }
        atomicAdd(accum, n8);
        atomicAdd(accum + 1, d8);
        __threadfence();
        unsigned int ticket = atomicAdd(counter, 1u);
        if (ticket == (unsigned int)(nblocks - 1)) {
            float tn = atomicAdd(accum, 0.0f);      // device-scope atomic read
            float td = atomicAdd(accum + 1, 0.0f);
            out[0] = tn / td;
        }
    }
}

extern "C" void kernel_launch(void* const* d_in, const int* in_sizes, int n_in,
                              void* d_out, int out_size, void* d_ws, size_t ws_size,
                              hipStream_t stream) {
    const float* V  = (const float*)d_in[0];
    const float* gt = (const float*)d_in[1];
    const float* W1 = (const float*)d_in[2];
    const float* b1 = (const float*)d_in[3];
    const float* W2 = (const float*)d_in[4];
    const float* b2 = (const float*)d_in[5];
    const float* W3 = (const float*)d_in[6];
    const float* b3 = (const float*)d_in[7];
    float* out = (float*)d_out;

    char* ws = (char*)d_ws;
    float* accum = (float*)ws;                     // [0]=num, [1]=den
    unsigned int* counter = (unsigned int*)(ws + 8);
    bf16_t* W2f = (bf16_t*)(ws + 16);
    bf16_t* W1f = (bf16_t*)(ws + 16 + 512 * 512 * 2);
    bf16_t* W3f = (bf16_t*)(ws + 16 + 512 * 512 * 2 + 32 * 512 * 2);

    int Brows = in_sizes[0] / IN_DIM;   // 131072
    int grid = Brows / M_TILE;          // 2048

    hipMemsetAsync(ws, 0, 16, stream);  // num, den, counter
    prep_kernel<<<72, 512, 0, stream>>>(W1, W2, W3, W1f, W2f, W3f);
    fused_kernel<<<grid, THREADS, 0, stream>>>(V, gt, b1, b2, b3, W1f, W2f, W3f,
                                               accum, counter, out, grid);
}

// Round 7
// 223.190 us; speedup vs baseline: 1.1360x; 1.1001x over previous
//
#include <hip/hip_runtime.h>
#include <hip/hip_bf16.h>

typedef __bf16 bf16_t;
typedef __bf16 bf16x8 __attribute__((ext_vector_type(8)));
typedef __bf16 bf16x4 __attribute__((ext_vector_type(4)));
typedef float f32x4 __attribute__((ext_vector_type(4)));

#define IN_DIM 21
#define HID 512
#define OUT_DIM 21
#define M_TILE 64
#define THREADS 1024  // 16 waves, f=2 (32 hid/wave): R2's spill-free economy + full unroll

// ---- prep: fp32 -> bf16 fragment-major weights + zero accum/counter ----
// frag element (idx = tile*16 + (lane&15), k = k0 + (lane>>4)*8 + j) at base + lane*8 + j.
// W2f: [kstep(16)][htile(32)][512]   W1f: [htile(32)][512] (k>=21 zero)
// W3f: [kstep(16)][otile(2)][512]    (o>=21 zero)
__global__ void prep_kernel(const float* __restrict__ W1, const float* __restrict__ W2,
                            const float* __restrict__ W3,
                            bf16_t* __restrict__ W1f, bf16_t* __restrict__ W2f,
                            bf16_t* __restrict__ W3f, float* __restrict__ accum) {
    int t8 = blockIdx.x * blockDim.x + threadIdx.x;   // one bf16x8 chunk per thread
    if (t8 < 4) accum[t8] = 0.0f;                     // num, den, counter, pad
    if (t8 < 32768) {                                 // W2f: 262144 elems / 8
        int lane = t8 & 63, ht = (t8 >> 6) & 31, ks = t8 >> 11;
        int n = ht * 16 + (lane & 15), k = ks * 32 + (lane >> 4) * 8;
        const float* src = W2 + n * HID + k;
        bf16x8 v;
        #pragma unroll
        for (int j = 0; j < 8; ++j) v[j] = (bf16_t)src[j];
        *reinterpret_cast<bf16x8*>(W2f + t8 * 8) = v;
    } else if (t8 < 32768 + 2048) {                   // W1f: 16384 / 8
        int t = t8 - 32768;
        int lane = t & 63, ht = t >> 6;
        int n = ht * 16 + (lane & 15), k0 = (lane >> 4) * 8;
        bf16x8 v;
        #pragma unroll
        for (int j = 0; j < 8; ++j) {
            int k = k0 + j;
            v[j] = (k < IN_DIM) ? (bf16_t)W1[n * IN_DIM + k] : (bf16_t)0.0f;
        }
        *reinterpret_cast<bf16x8*>(W1f + t * 8) = v;
    } else if (t8 < 32768 + 4096) {                   // W3f: 16384 / 8
        int t = t8 - 32768 - 2048;
        int lane = t & 63, ot = (t >> 6) & 1, ks = t >> 7;
        int o = ot * 16 + (lane & 15), k = ks * 32 + (lane >> 4) * 8;
        bf16x8 v;
        #pragma unroll
        for (int j = 0; j < 8; ++j)
            v[j] = (o < OUT_DIM) ? (bf16_t)W3[o * HID + k + j] : (bf16_t)0.0f;
        *reinterpret_cast<bf16x8*>(W3f + t * 8) = v;
    }
}

// ---- fused MLP + loss; fragment-major LDS; full-unroll K-loop (compiler pipelines) ----
__global__ __launch_bounds__(THREADS)
void fused_kernel(const float* __restrict__ V, const float* __restrict__ gt,
                  const float* __restrict__ b1, const float* __restrict__ b2,
                  const float* __restrict__ b3,
                  const bf16_t* __restrict__ W1f, const bf16_t* __restrict__ W2f,
                  const bf16_t* __restrict__ W3f, float* __restrict__ accum,
                  unsigned int* __restrict__ counter, float* __restrict__ out,
                  int nblocks) {
    // hfrag[kgroup][btile][lane][j]: element (batch = btile*16 + (lane&15),
    //   hid = kgroup*32 + (lane>>4)*8 + j). Wave B-frag read = contiguous 1 KB.
    __shared__ __align__(16) bf16_t hfrag[16][4][64][8];   // 64 KB, h1 then h2
    __shared__ __align__(16) bf16_t vfrag[4][64][8];       // 4 KB, V tile
    __shared__ float redbuf[16];

    const int tid  = threadIdx.x;
    const int wave = tid >> 6;       // 0..15; owns hid [wave*32, wave*32+32)
    const int lane = tid & 63;
    const int quad = lane >> 4;
    const int l16  = lane & 15;
    const long row0 = (long)blockIdx.x * M_TILE;

    // phase 0: stage V tile into vfrag (fragment-major, k cols >=21 zero)
    if (tid < 256) {
        int nt = tid >> 6, ln = tid & 63;
        int batch = nt * 16 + (ln & 15);
        int k0 = (ln >> 4) * 8;
        const float* src = V + (row0 + batch) * IN_DIM;
        bf16x8 v;
        #pragma unroll
        for (int j = 0; j < 8; ++j) {
            int k = k0 + j;
            v[j] = (k < IN_DIM) ? (bf16_t)src[k] : (bf16_t)0.0f;
        }
        *reinterpret_cast<bf16x8*>(&vfrag[nt][ln][0]) = v;
    }
    __syncthreads();

    // phase 1: h1 = relu(W1 @ V^T + b1); D[m=hid][n=batch]; 2 m-tiles/wave
    {
        bf16x8 bfr[4];
        #pragma unroll
        for (int nt = 0; nt < 4; ++nt)
            bfr[nt] = *reinterpret_cast<const bf16x8*>(&vfrag[nt][lane][0]);
        #pragma unroll
        for (int t = 0; t < 2; ++t) {
            bf16x8 a = *reinterpret_cast<const bf16x8*>(W1f + (wave * 2 + t) * 512 + lane * 8);
            f32x4 bias = *reinterpret_cast<const f32x4*>(b1 + wave * 32 + t * 16 + quad * 4);
            #pragma unroll
            for (int nt = 0; nt < 4; ++nt) {
                f32x4 c = {0.0f, 0.0f, 0.0f, 0.0f};
                c = __builtin_amdgcn_mfma_f32_16x16x32_bf16(a, bfr[nt], c, 0, 0, 0);
                bf16x4 hv;
                #pragma unroll
                for (int r = 0; r < 4; ++r) {
                    float v = c[r] + bias[r];
                    hv[r] = (bf16_t)(v > 0.0f ? v : 0.0f);
                }
                // hid = wave*32 + t*16 + quad*4 + r -> kg=wave, khi=t*16+quad*4+r
                *reinterpret_cast<bf16x4*>(
                    &hfrag[wave][nt][l16 + 16 * (t * 2 + (quad >> 1))][(quad & 1) * 4]) = hv;
            }
        }
    }
    __syncthreads();

    // phase 2: h2 = relu(W2 @ h1^T + b2). Per wave: 32 hid x 64 batch, K=512.
    // Full unroll, no manual prefetch: compiler software-pipelines the global
    // loads multiple iterations deep (R2 evidence: best time came from this).
    f32x4 acc[2][4];
    #pragma unroll
    for (int t = 0; t < 2; ++t)
        #pragma unroll
        for (int nt = 0; nt < 4; ++nt)
            acc[t][nt] = (f32x4){0.0f, 0.0f, 0.0f, 0.0f};

    #pragma unroll
    for (int ks = 0; ks < 16; ++ks) {
        const bf16_t* wp = W2f + ks * 16384 + (wave * 2) * 512 + lane * 8;
        bf16x8 a0 = *reinterpret_cast<const bf16x8*>(wp);
        bf16x8 a1 = *reinterpret_cast<const bf16x8*>(wp + 512);
        bf16x8 b0 = *reinterpret_cast<const bf16x8*>(&hfrag[ks][0][lane][0]);
        bf16x8 b1v = *reinterpret_cast<const bf16x8*>(&hfrag[ks][1][lane][0]);
        bf16x8 b2v = *reinterpret_cast<const bf16x8*>(&hfrag[ks][2][lane][0]);
        bf16x8 b3v = *reinterpret_cast<const bf16x8*>(&hfrag[ks][3][lane][0]);
        acc[0][0] = __builtin_amdgcn_mfma_f32_16x16x32_bf16(a0, b0,  acc[0][0], 0, 0, 0);
        acc[1][0] = __builtin_amdgcn_mfma_f32_16x16x32_bf16(a1, b0,  acc[1][0], 0, 0, 0);
        acc[0][1] = __builtin_amdgcn_mfma_f32_16x16x32_bf16(a0, b1v, acc[0][1], 0, 0, 0);
        acc[1][1] = __builtin_amdgcn_mfma_f32_16x16x32_bf16(a1, b1v, acc[1][1], 0, 0, 0);
        acc[0][2] = __builtin_amdgcn_mfma_f32_16x16x32_bf16(a0, b2v, acc[0][2], 0, 0, 0);
        acc[1][2] = __builtin_amdgcn_mfma_f32_16x16x32_bf16(a1, b2v, acc[1][2], 0, 0, 0);
        acc[0][3] = __builtin_amdgcn_mfma_f32_16x16x32_bf16(a0, b3v, acc[0][3], 0, 0, 0);
        acc[1][3] = __builtin_amdgcn_mfma_f32_16x16x32_bf16(a1, b3v, acc[1][3], 0, 0, 0);
    }
    __syncthreads();   // all h1 reads complete before overwrite

    #pragma unroll
    for (int t = 0; t < 2; ++t) {
        f32x4 bias = *reinterpret_cast<const f32x4*>(b2 + wave * 32 + t * 16 + quad * 4);
        #pragma unroll
        for (int nt = 0; nt < 4; ++nt) {
            bf16x4 hv;
            #pragma unroll
            for (int r = 0; r < 4; ++r) {
                float v = acc[t][nt][r] + bias[r];
                hv[r] = (bf16_t)(v > 0.0f ? v : 0.0f);
            }
            *reinterpret_cast<bf16x4*>(
                &hfrag[wave][nt][l16 + 16 * (t * 2 + (quad >> 1))][(quad & 1) * 4]) = hv;
        }
    }
    __syncthreads();

    // phase 3: out = W3 @ h2^T + b3. 8 jobs = 2 o-tiles x 4 batch-tiles on waves 0..7.
    if (wave < 8) {
        const int ot = wave & 1, ntj = wave >> 1;
        f32x4 acc3 = {0.0f, 0.0f, 0.0f, 0.0f};
        #pragma unroll
        for (int ks = 0; ks < 16; ++ks) {
            bf16x8 a = *reinterpret_cast<const bf16x8*>(W3f + (ks * 2 + ot) * 512 + lane * 8);
            bf16x8 b = *reinterpret_cast<const bf16x8*>(&hfrag[ks][ntj][lane][0]);
            acc3 = __builtin_amdgcn_mfma_f32_16x16x32_bf16(a, b, acc3, 0, 0, 0);
        }

        float num = 0.0f, den = 0.0f;
        long brow = row0 + ntj * 16 + l16;
        #pragma unroll
        for (int r = 0; r < 4; ++r) {
            int c = ot * 16 + quad * 4 + r;
            if (c < OUT_DIM) {
                float pred = acc3[r] + b3[c];
                float g = gt[brow * OUT_DIM + c];
                if (g > -5000.0f) {
                    float w = (floorf(pred * 2.0f) == floorf(g * 2.0f)) ? 0.5f : 1.0f;
                    num += fabsf(pred * w - g * w);
                    den += 1.0f;
                }
            }
        }
        #pragma unroll
        for (int off = 32; off > 0; off >>= 1) {
            num += __shfl_down(num, off);
            den += __shfl_down(den, off);
        }
        if (lane == 0) { redbuf[wave * 2] = num; redbuf[wave * 2 + 1] = den; }
    }
    __syncthreads();
    if (tid == 0) {
        float n8 = 0.0f, d8 = 0.0f;
        #pragma unroll
        for (int w = 0; w < 8; ++w) { n8 += redbuf[w * 2]; d8 += redbuf[w * 2 + 1]; }
        atomicAdd(accum, n8);
        atomicAdd(accum + 1, d8);
        __threadfence();
        unsigned int ticket = atomicAdd(counter, 1u);
        if (ticket == (unsigned int)(nblocks - 1)) {
            float tn = atomicAdd(accum, 0.0f);      // device-scope atomic read
            float td = atomicAdd(accum + 1, 0.0f);
            out[0] = tn / td;
        }
    }
}

extern "C" void kernel_launch(void* const* d_in, const int* in_sizes, int n_in,
                              void* d_out, int out_size, void* d_ws, size_t ws_size,
                              hipStream_t stream) {
    const float* V  = (const float*)d_in[0];
    const float* gt = (const float*)d_in[1];
    const float* W1 = (const float*)d_in[2];
    const float* b1 = (const float*)d_in[3];
    const float* W2 = (const float*)d_in[4];
    const float* b2 = (const float*)d_in[5];
    const float* W3 = (const float*)d_in[6];
    const float* b3 = (const float*)d_in[7];
    float* out = (float*)d_out;

    char* ws = (char*)d_ws;
    float* accum = (float*)ws;                     // [0]=num, [1]=den, [2]=counter
    unsigned int* counter = (unsigned int*)(ws + 8);
    bf16_t* W2f = (bf16_t*)(ws + 16);
    bf16_t* W1f = (bf16_t*)(ws + 16 + 512 * 512 * 2);
    bf16_t* W3f = (bf16_t*)(ws + 16 + 512 * 512 * 2 + 32 * 512 * 2);

    int Brows = in_sizes[0] / IN_DIM;   // 131072
    int grid = Brows / M_TILE;          // 2048

    prep_kernel<<<72, 512, 0, stream>>>(W1, W2, W3, W1f, W2f, W3f, accum);
    fused_kernel<<<grid, THREADS, 0, stream>>>(V, gt, b1, b2, b3, W1f, W2f, W3f,
                                               accum, counter, out, grid);
}